// Round 12
// baseline (1078.410 us; speedup 1.0000x reference)
//
#include <hip/hip_runtime.h>
#include <hip/hip_bf16.h>
#include <cstdint>

typedef unsigned int uint32;
typedef unsigned short ushort;
typedef __attribute__((ext_vector_type(8))) short short8;   // 8 bf16 (4 VGPRs)
typedef __attribute__((ext_vector_type(4))) float f32x4;    // MFMA C/D

#define EPB 4096      // edges per virtual block in partition phase
#define CAP 8192      // slots per 256-node bucket (mean ~4081, 2x headroom)
#define NBLK 1024     // persistent blocks: 4/CU x 256 CU (exact co-residency)

__device__ inline ushort bf16r(float f) {
    uint32 u = __float_as_uint(f);
    u += 0x7fff + ((u >> 16) & 1);
    return (ushort)(u >> 16);
}
__device__ inline uint32 pack_bf16(float a, float b) {
    return (uint32)bf16r(a) | ((uint32)bf16r(b) << 16);
}
__device__ inline float bf_lo(uint32 w) { return __uint_as_float(w << 16); }
__device__ inline float bf_hi(uint32 w) { return __uint_as_float(w & 0xffff0000u); }

// device-scope generation barrier. bar[0]=cnt, bar[1]=gen (memset to 0 each call).
__device__ __forceinline__ void gbar(int* bar) {
    __syncthreads();
    if (threadIdx.x == 0) {
        __threadfence();   // release: wb this XCD's L2
        int g = __hip_atomic_load(&bar[1], __ATOMIC_RELAXED, __HIP_MEMORY_SCOPE_AGENT);
        int a = __hip_atomic_fetch_add(&bar[0], 1, __ATOMIC_RELAXED, __HIP_MEMORY_SCOPE_AGENT);
        if (a == NBLK - 1) {
            __hip_atomic_store(&bar[0], 0, __ATOMIC_RELAXED, __HIP_MEMORY_SCOPE_AGENT);
            __threadfence();
            __hip_atomic_fetch_add(&bar[1], 1, __ATOMIC_RELAXED, __HIP_MEMORY_SCOPE_AGENT);
        } else {
            while (__hip_atomic_load(&bar[1], __ATOMIC_RELAXED, __HIP_MEMORY_SCOPE_AGENT) == g)
                __builtin_amdgcn_s_sleep(2);
            __threadfence();   // acquire: inv this CU's L1 + XCD L2
        }
    }
    __syncthreads();
}

// ---------------- mega kernel: CSR build + 3 GCN layers, 8 grid barriers ----------------

__global__ __launch_bounds__(256, 4) void k_mega(
        const float* __restrict__ x,
        const float* __restrict__ W1, const float* __restrict__ b1,
        const float* __restrict__ W2, const float* __restrict__ b2,
        const float* __restrict__ W3, const float* __restrict__ b3,
        const int* __restrict__ srcv, const int* __restrict__ dstv,
        int N, int E, int NB, int nbE,
        int* bcnt, int* bar, uint64_t* pairs, int2* rps, float* dis, int* col,
        ushort* Wt1, ushort* Wt2, ushort* Wt3,
        ushort* hsb, ushort* hbX, ushort* hs3, float* outp) {
    __shared__ int sh[768];
    int t = threadIdx.x;
    int lane = t & 63;
    int wid = t >> 6;

    // ---- phase A: bucket partition (+ W transpose prep) ----
    for (int vb = blockIdx.x; vb < nbE + 3; vb += NBLK) {
        if (vb >= nbE) {
            int wb = vb - nbE;
            const float* W = wb == 0 ? W1 : (wb == 1 ? W2 : W3);
            ushort* Wt = wb == 0 ? Wt1 : (wb == 1 ? Wt2 : Wt3);
            int F = wb == 2 ? 64 : 128;
            for (int i = t; i < 128 * F; i += 256) {
                int k = i / F, c = i % F;
                Wt[c * 128 + k] = bf16r(W[i]);
            }
        } else {
            int* h = sh; int* base = sh + 256; int* cur = sh + 512;
            h[t] = 0; cur[t] = 0;
            __syncthreads();
            int s[EPB / 256], d[EPB / 256];
            int b0 = vb * EPB;
#pragma unroll
            for (int i = 0; i < EPB / 256; ++i) {
                int idx = b0 + i * 256 + t;
                if (idx < E) {
                    s[i] = srcv[idx]; d[i] = dstv[idx];
                    atomicAdd(&h[d[i] >> 8], 1);
                } else d[i] = -1;
            }
            __syncthreads();
            base[t] = h[t] ? atomicAdd(&bcnt[t], h[t]) : 0;
            __syncthreads();
#pragma unroll
            for (int i = 0; i < EPB / 256; ++i) {
                if (d[i] >= 0) {
                    int b = d[i] >> 8;
                    int sl = base[b] + atomicAdd(&cur[b], 1);
                    if (sl < CAP)
                        pairs[(size_t)b * CAP + sl] =
                            (uint64_t)(unsigned)s[i] | ((uint64_t)(unsigned)d[i] << 32);
                }
            }
            __syncthreads();   // protect LDS for next virtual block
        }
    }
    gbar(bar);

    // ---- phase B: per-bucket CSR finish ----
    for (int vb = blockIdx.x; vb < NB; vb += NBLK) {
        int* c = sh; int* sc = sh + 256; int* cur = sh + 512;
        c[t] = 0; cur[t] = 0;
        __syncthreads();
        int wb = vb << 8;
        int e0 = vb * CAP;
        int e1 = e0 + min(bcnt[vb], CAP);
        for (int i = e0 + t; i < e1; i += 256)
            atomicAdd(&c[(int)(pairs[i] >> 32) - wb], 1);
        __syncthreads();
        int own = c[t];
        sc[t] = own;
        __syncthreads();
        for (int off = 1; off < 256; off <<= 1) {
            int a = (t >= off) ? sc[t - off] : 0;
            __syncthreads();
            sc[t] += a;
            __syncthreads();
        }
        int start = vb * CAP + sc[t] - own;
        __syncthreads();
        sc[t] = start;
        int v = wb + t;
        if (v < N) {
            rps[v] = make_int2(start, start + own);
            dis[v] = rsqrtf((float)(own + 1));
        }
        __syncthreads();
        for (int i = e0 + t; i < e1; i += 256) {
            uint64_t p = pairs[i];
            int bl = (int)(p >> 32) - wb;
            int sl = atomicAdd(&cur[bl], 1);
            col[sc[bl] + sl] = (int)(uint32)p;
        }
        __syncthreads();
    }
    gbar(bar);

    const int gblk = (N + 63) / 64;
    const int ablk = (N + 3) / 4;
    int r16 = lane & 15, kg = lane >> 4;

    // ---- GEMM phase macro (register-resident, Wt from L2) ----
#define GEMM_PHASE(FOUT, BF16IN, XPTR, WTPTR, YPTR)                                   \
    for (int vb = blockIdx.x; vb < gblk; vb += NBLK) {                                \
        constexpr int CT = (FOUT) / 16;                                               \
        int rowA = vb * 64 + wid * 16 + r16;                                          \
        int ra = min(rowA, N - 1);                                                    \
        short8 afr[4];                                                                \
        if (BF16IN) {                                                                 \
            const ushort* Xb = (const ushort*)(XPTR);                                 \
            _Pragma("unroll")                                                         \
            for (int ks = 0; ks < 4; ++ks)                                            \
                afr[ks] = *(const short8*)(Xb + (size_t)ra * 128 + ks * 32 + kg * 8); \
        } else {                                                                      \
            const float* Xf = (const float*)(XPTR);                                   \
            _Pragma("unroll")                                                         \
            for (int ks = 0; ks < 4; ++ks) {                                          \
                const float* p = Xf + (size_t)ra * 128 + ks * 32 + kg * 8;            \
                float4 f0 = *(const float4*)p;                                        \
                float4 f1 = *(const float4*)(p + 4);                                  \
                short8 a;                                                             \
                a[0] = (short)bf16r(f0.x); a[1] = (short)bf16r(f0.y);                 \
                a[2] = (short)bf16r(f0.z); a[3] = (short)bf16r(f0.w);                 \
                a[4] = (short)bf16r(f1.x); a[5] = (short)bf16r(f1.y);                 \
                a[6] = (short)bf16r(f1.z); a[7] = (short)bf16r(f1.w);                 \
                afr[ks] = a;                                                          \
            }                                                                         \
        }                                                                             \
        f32x4 acc[CT];                                                                \
        _Pragma("unroll")                                                             \
        for (int c = 0; c < CT; ++c) acc[c] = (f32x4){0.f, 0.f, 0.f, 0.f};            \
        _Pragma("unroll")                                                             \
        for (int ks = 0; ks < 4; ++ks) {                                              \
            _Pragma("unroll")                                                         \
            for (int c = 0; c < CT; ++c) {                                            \
                short8 b = *(const short8*)((WTPTR) + (c * 16 + r16) * 128 + ks * 32 + kg * 8); \
                acc[c] = __builtin_amdgcn_mfma_f32_16x16x32_bf16(afr[ks], b, acc[c], 0, 0, 0); \
            }                                                                         \
        }                                                                             \
        int rbase = vb * 64 + wid * 16 + kg * 4;                                      \
        _Pragma("unroll")                                                             \
        for (int j = 0; j < 4; ++j) {                                                 \
            int row = rbase + j;                                                      \
            if (row < N) {                                                            \
                float dd = dis[row];                                                  \
                _Pragma("unroll")                                                     \
                for (int c = 0; c < CT; ++c)                                          \
                    (YPTR)[(size_t)row * (FOUT) + c * 16 + r16] = bf16r(acc[c][j] * dd); \
            }                                                                         \
        }                                                                             \
    }

    // ---- agg phase macro (16-wide batched bf16 gathers, F=128) ----
#define AGG_PHASE(HB, BIAS, OUTB)                                                     \
    for (int vb = blockIdx.x; vb < ablk; vb += NBLK) {                                \
        int v = vb * 4 + wid;                                                         \
        if (v < N) {                                                                  \
            const uint32* hb = (const uint32*)(HB);                                   \
            uint32 mv = hb[(size_t)v * 64 + lane];                                    \
            float ax = bf_lo(mv), ay = bf_hi(mv);                                     \
            int2 se = rps[v];                                                         \
            int s = __builtin_amdgcn_readfirstlane(se.x);                             \
            int e = __builtin_amdgcn_readfirstlane(se.y);                             \
            int k = s;                                                                \
            for (; k + 16 <= e; k += 16) {                                            \
                uint32 m[16];                                                         \
                _Pragma("unroll")                                                     \
                for (int j = 0; j < 16; ++j) m[j] = hb[(size_t)col[k + j] * 64 + lane]; \
                _Pragma("unroll")                                                     \
                for (int j = 0; j < 16; ++j) { ax += bf_lo(m[j]); ay += bf_hi(m[j]); } \
            }                                                                         \
            if (k + 8 <= e) {                                                         \
                uint32 m[8];                                                          \
                _Pragma("unroll")                                                     \
                for (int j = 0; j < 8; ++j) m[j] = hb[(size_t)col[k + j] * 64 + lane]; \
                _Pragma("unroll")                                                     \
                for (int j = 0; j < 8; ++j) { ax += bf_lo(m[j]); ay += bf_hi(m[j]); } \
                k += 8;                                                               \
            }                                                                         \
            if (k + 4 <= e) {                                                         \
                uint32 m[4];                                                          \
                _Pragma("unroll")                                                     \
                for (int j = 0; j < 4; ++j) m[j] = hb[(size_t)col[k + j] * 64 + lane]; \
                _Pragma("unroll")                                                     \
                for (int j = 0; j < 4; ++j) { ax += bf_lo(m[j]); ay += bf_hi(m[j]); } \
                k += 4;                                                               \
            }                                                                         \
            for (; k < e; ++k) {                                                      \
                uint32 m = hb[(size_t)col[k] * 64 + lane];                            \
                ax += bf_lo(m); ay += bf_hi(m);                                       \
            }                                                                         \
            float dd = dis[v];                                                        \
            float2 bb = ((const float2*)(BIAS))[lane];                                \
            float ox = fmaxf(dd * ax + bb.x, 0.f);                                    \
            float oy = fmaxf(dd * ay + bb.y, 0.f);                                    \
            ((uint32*)(OUTB))[(size_t)v * 64 + lane] = pack_bf16(ox, oy);             \
        }                                                                             \
    }

    // ---- layer 1 ----
    GEMM_PHASE(128, false, x, Wt1, hsb)
    gbar(bar);
    AGG_PHASE(hsb, b1, hbX)
    gbar(bar);
    // ---- layer 2 ----
    GEMM_PHASE(128, true, hbX, Wt2, hsb)
    gbar(bar);
    AGG_PHASE(hsb, b2, hbX)
    gbar(bar);
    // ---- layer 3 ----
    GEMM_PHASE(64, true, hbX, Wt3, hs3)
    gbar(bar);

    // ---- final: F=64 gather + bias + log_softmax ----
    for (int vb = blockIdx.x; vb < ablk; vb += NBLK) {
        int v = vb * 4 + wid;
        if (v < N) {
            float acc = __uint_as_float((uint32)hs3[(size_t)v * 64 + lane] << 16);
            int2 se = rps[v];
            int s = __builtin_amdgcn_readfirstlane(se.x);
            int e = __builtin_amdgcn_readfirstlane(se.y);
            int k = s;
            for (; k + 16 <= e; k += 16) {
                ushort m[16];
#pragma unroll
                for (int j = 0; j < 16; ++j) m[j] = hs3[(size_t)col[k + j] * 64 + lane];
#pragma unroll
                for (int j = 0; j < 16; ++j) acc += __uint_as_float((uint32)m[j] << 16);
            }
            if (k + 8 <= e) {
                ushort m[8];
#pragma unroll
                for (int j = 0; j < 8; ++j) m[j] = hs3[(size_t)col[k + j] * 64 + lane];
#pragma unroll
                for (int j = 0; j < 8; ++j) acc += __uint_as_float((uint32)m[j] << 16);
                k += 8;
            }
            for (; k < e; ++k) acc += __uint_as_float((uint32)hs3[(size_t)col[k] * 64 + lane] << 16);
            float val = dis[v] * acc + b3[lane];
            float mx = val;
            for (int off = 32; off; off >>= 1) mx = fmaxf(mx, __shfl_xor(mx, off, 64));
            float ex = expf(val - mx);
            float ss = ex;
            for (int off = 32; off; off >>= 1) ss += __shfl_xor(ss, off, 64);
            __builtin_nontemporal_store(val - mx - logf(ss), &outp[(size_t)v * 64 + lane]);
        }
    }
#undef GEMM_PHASE
#undef AGG_PHASE
}

// ---------------- launch ----------------

extern "C" void kernel_launch(void* const* d_in, const int* in_sizes, int n_in,
                              void* d_out, int out_size, void* d_ws, size_t ws_size,
                              hipStream_t stream) {
    const float* x  = (const float*)d_in[0];
    const float* W1 = (const float*)d_in[1];
    const float* b1 = (const float*)d_in[2];
    const float* W2 = (const float*)d_in[3];
    const float* b2 = (const float*)d_in[4];
    const float* W3 = (const float*)d_in[5];
    const float* b3 = (const float*)d_in[6];
    const int*   ei = (const int*)d_in[7];

    const int N = in_sizes[0] / 128;
    const int E = in_sizes[7] / 2;
    const int* srcv = ei;
    const int* dstv = ei + E;
    const int NB  = (N + 255) >> 8;          // 256-node buckets
    const int nbE = (E + EPB - 1) / EPB;

    char* ws = (char*)d_ws;
    size_t off = 0;
    auto alloc = [&](size_t bytes) -> void* {
        void* p = ws + off;
        off += (bytes + 255) & ~(size_t)255;
        return p;
    };
    int*      bcnt  = (int*)alloc((size_t)(NB + 2) * 4);   // bcnt[NB] + bar[2], one memset
    int*      bar   = bcnt + NB;
    float*    dis   = (float*)alloc((size_t)N * 4);
    int2*     rps   = (int2*)alloc((size_t)N * 8);
    int*      col   = (int*)alloc((size_t)NB * CAP * 4);
    uint64_t* pairs = (uint64_t*)alloc((size_t)NB * CAP * 8);
    ushort*   Wt1   = (ushort*)alloc(128 * 128 * 2);
    ushort*   Wt2   = (ushort*)alloc(128 * 128 * 2);
    ushort*   Wt3   = (ushort*)alloc(64 * 128 * 2);
    ushort*   hsb   = (ushort*)alloc((size_t)N * 128 * 2);  // GEMM out / gather src
    ushort*   hbX   = (ushort*)alloc((size_t)N * 128 * 2);  // agg out / GEMM in
    ushort*   hs3   = (ushort*)alloc((size_t)N * 64 * 2);   // GEMM3 out
    float*    outp  = (float*)d_out;

    (void)hipMemsetAsync(bcnt, 0, (size_t)(NB + 2) * 4, stream);
    k_mega<<<NBLK, 256, 0, stream>>>(x, W1, b1, W2, b2, W3, b3, srcv, dstv,
                                     N, E, NB, nbE,
                                     bcnt, bar, pairs, rps, dis, col,
                                     Wt1, Wt2, Wt3, hsb, hbX, hs3, outp);
}

// Round 13
// 211.108 us; speedup vs baseline: 5.1083x; 5.1083x over previous
//
#include <hip/hip_runtime.h>
#include <hip/hip_bf16.h>
#include <cstdint>

typedef unsigned int uint32;
typedef unsigned short ushort;
typedef __attribute__((ext_vector_type(8))) short short8;   // 8 bf16 (4 VGPRs)
typedef __attribute__((ext_vector_type(4))) float f32x4;    // MFMA C/D

#define EPB 4096      // edges per block in partition kernel
#define CAP 8192      // slots per 256-node bucket (mean ~4081, 2x headroom)

__device__ inline ushort bf16r(float f) {
    uint32 u = __float_as_uint(f);
    u += 0x7fff + ((u >> 16) & 1);
    return (ushort)(u >> 16);
}
__device__ inline float bfu(ushort w) { return __uint_as_float((uint32)w << 16); }

// ---------------- K1: direct bucket partition + W-prep ----------------
// bucket = dst >> 8 (256-node windows, NB<=256). pairs bucket-strided by CAP.

__global__ __launch_bounds__(256) void k_part_prep(
        const int* __restrict__ srcv, const int* __restrict__ dstv,
        int* __restrict__ bcnt, uint64_t* __restrict__ pairs, int e, int nbE,
        const float* __restrict__ W1, const float* __restrict__ W2, const float* __restrict__ W3,
        ushort* __restrict__ Wt1, ushort* __restrict__ Wt2, ushort* __restrict__ Wt3) {
    int bid = blockIdx.x, t = threadIdx.x;
    if (bid >= nbE) {
        int wb = bid - nbE;
        const float* W = wb == 0 ? W1 : (wb == 1 ? W2 : W3);
        ushort* Wt = wb == 0 ? Wt1 : (wb == 1 ? Wt2 : Wt3);
        int F = wb == 2 ? 64 : 128;
        for (int i = t; i < 128 * F; i += 256) {
            int k = i / F, c = i % F;
            Wt[c * 128 + k] = bf16r(W[i]);
        }
        return;
    }
    __shared__ int h[256], base[256], cur[256];
    h[t] = 0; cur[t] = 0;
    __syncthreads();
    int s[EPB / 256], d[EPB / 256];
    int b0 = bid * EPB;
#pragma unroll
    for (int i = 0; i < EPB / 256; ++i) {
        int idx = b0 + i * 256 + t;
        if (idx < e) {
            s[i] = srcv[idx]; d[i] = dstv[idx];
            atomicAdd(&h[d[i] >> 8], 1);
        } else d[i] = -1;
    }
    __syncthreads();
    base[t] = h[t] ? atomicAdd(&bcnt[t], h[t]) : 0;
    __syncthreads();
#pragma unroll
    for (int i = 0; i < EPB / 256; ++i) {
        if (d[i] >= 0) {
            int b = d[i] >> 8;
            int sl = base[b] + atomicAdd(&cur[b], 1);
            if (sl < CAP)
                pairs[(size_t)b * CAP + sl] =
                    (uint64_t)(unsigned)s[i] | ((uint64_t)(unsigned)d[i] << 32);
        }
    }
}

// ---------------- K2: per-bucket finish — local CSR into bucket-strided col ----------------

__global__ __launch_bounds__(256) void k_bfinish(const uint64_t* __restrict__ pairs,
                                                 const int* __restrict__ bcnt,
                                                 int2* __restrict__ rps, float* __restrict__ dis,
                                                 int* __restrict__ col, int n) {
    __shared__ int c[256], sc[256], cur[256];
    int t = threadIdx.x;
    c[t] = 0; cur[t] = 0;
    __syncthreads();
    int wb = blockIdx.x << 8;
    int e0 = blockIdx.x * CAP;
    int e1 = e0 + min(bcnt[blockIdx.x], CAP);
    for (int i = e0 + t; i < e1; i += 256)
        atomicAdd(&c[(int)(pairs[i] >> 32) - wb], 1);
    __syncthreads();
    int own = c[t];
    sc[t] = own;
    __syncthreads();
    for (int off = 1; off < 256; off <<= 1) {
        int a = (t >= off) ? sc[t - off] : 0;
        __syncthreads();
        sc[t] += a;
        __syncthreads();
    }
    int start = blockIdx.x * CAP + sc[t] - own;
    __syncthreads();
    sc[t] = start;
    int v = wb + t;
    if (v < n) {
        rps[v] = make_int2(start, start + own);
        dis[v] = rsqrtf((float)(own + 1));
    }
    __syncthreads();
    for (int i = e0 + t; i < e1; i += 256) {
        uint64_t p = pairs[i];
        int bl = (int)(p >> 32) - wb;
        int sl = atomicAdd(&cur[bl], 1);
        col[sc[bl] + sl] = (int)(uint32)p;
    }
}

// ------- MFMA GEMM: Y[r][c] = bf16( dis[r] * sum_k X[r][k] * W[k][c] ) -------
// INMODE: 0 = fp32 flat [N][128], 1 = bf16 planar (2 planes of [N][64])
// FOUT=128 -> planar output (2 planes of [N][64]); FOUT=64 -> flat [N][64]

template <int FOUT, int INMODE>
__global__ __launch_bounds__(256) void k_gemm_mfma(
        const void* __restrict__ Xv, const ushort* __restrict__ Wt,
        const float* __restrict__ dis, ushort* __restrict__ Yb, int n, size_t plsz) {
    constexpr int CT = FOUT / 16;
    int lane = threadIdx.x & 63;
    int wv = threadIdx.x >> 6;
    int r16 = lane & 15, kg = lane >> 4;
    int rowA = blockIdx.x * 64 + wv * 16 + r16;
    int ra = min(rowA, n - 1);
    short8 afr[4];
    if (INMODE == 1) {
        const ushort* Xb = (const ushort*)Xv;
#pragma unroll
        for (int ks = 0; ks < 4; ++ks)
            afr[ks] = *(const short8*)(Xb + (size_t)(ks >> 1) * plsz +
                                       (size_t)ra * 64 + (ks & 1) * 32 + kg * 8);
    } else {
        const float* Xf = (const float*)Xv;
#pragma unroll
        for (int ks = 0; ks < 4; ++ks) {
            const float* p = Xf + (size_t)ra * 128 + ks * 32 + kg * 8;
            float4 f0 = *(const float4*)p;
            float4 f1 = *(const float4*)(p + 4);
            short8 a;
            a[0] = (short)bf16r(f0.x); a[1] = (short)bf16r(f0.y);
            a[2] = (short)bf16r(f0.z); a[3] = (short)bf16r(f0.w);
            a[4] = (short)bf16r(f1.x); a[5] = (short)bf16r(f1.y);
            a[6] = (short)bf16r(f1.z); a[7] = (short)bf16r(f1.w);
            afr[ks] = a;
        }
    }
    f32x4 acc[CT];
#pragma unroll
    for (int c = 0; c < CT; ++c) acc[c] = (f32x4){0.f, 0.f, 0.f, 0.f};
#pragma unroll
    for (int ks = 0; ks < 4; ++ks) {
#pragma unroll
        for (int c = 0; c < CT; ++c) {
            short8 b = *(const short8*)(Wt + (c * 16 + r16) * 128 + ks * 32 + kg * 8);
            acc[c] = __builtin_amdgcn_mfma_f32_16x16x32_bf16(afr[ks], b, acc[c], 0, 0, 0);
        }
    }
    int rbase = blockIdx.x * 64 + wv * 16 + kg * 4;
#pragma unroll
    for (int j = 0; j < 4; ++j) {
        int row = rbase + j;
        if (row < n) {
            float d = dis[row];
#pragma unroll
            for (int c = 0; c < CT; ++c) {
                ushort val = bf16r(acc[c][j] * d);
                if (FOUT == 128)
                    Yb[(size_t)(c >> 2) * plsz + (size_t)row * 64 + (c & 3) * 16 + r16] = val;
                else
                    Yb[(size_t)row * 64 + c * 16 + r16] = val;
            }
        }
    }
}

// ------- aggregation over ONE 64-feature plane: 1 node/wave, lane = feature -------
// outp[v][lane] = bf16( relu( dis[v] * (hp[v] + sum_nbr hp[u]) + bias ) )

__global__ __launch_bounds__(256) void k_agg_plane(
        const ushort* __restrict__ hp, const int2* __restrict__ rps,
        const int* __restrict__ col, const float* __restrict__ dis,
        const float* __restrict__ bias, ushort* __restrict__ outp, int n) {
    int wid = threadIdx.x >> 6;
    int lane = threadIdx.x & 63;
    int v = blockIdx.x * 4 + wid;
    if (v >= n) return;
    float ax = bfu(hp[(size_t)v * 64 + lane]);   // self-loop term
    int2 se = rps[v];
    int s = __builtin_amdgcn_readfirstlane(se.x);
    int e = __builtin_amdgcn_readfirstlane(se.y);
    int k = s;
    for (; k + 16 <= e; k += 16) {
        ushort m[16];
#pragma unroll
        for (int j = 0; j < 16; ++j) m[j] = hp[(size_t)col[k + j] * 64 + lane];
#pragma unroll
        for (int j = 0; j < 16; ++j) ax += bfu(m[j]);
    }
    if (k + 8 <= e) {
        ushort m[8];
#pragma unroll
        for (int j = 0; j < 8; ++j) m[j] = hp[(size_t)col[k + j] * 64 + lane];
#pragma unroll
        for (int j = 0; j < 8; ++j) ax += bfu(m[j]);
        k += 8;
    }
    if (k + 4 <= e) {
        ushort m[4];
#pragma unroll
        for (int j = 0; j < 4; ++j) m[j] = hp[(size_t)col[k + j] * 64 + lane];
#pragma unroll
        for (int j = 0; j < 4; ++j) ax += bfu(m[j]);
        k += 4;
    }
    for (; k < e; ++k) ax += bfu(hp[(size_t)col[k] * 64 + lane]);
    float ox = fmaxf(dis[v] * ax + bias[lane], 0.f);
    __builtin_nontemporal_store(bf16r(ox), &outp[(size_t)v * 64 + lane]);
}

// final layer: F=64 flat bf16 rows, fused bias + log_softmax (fp32 out)
__global__ __launch_bounds__(256) void k_agg_lsm64(
        const ushort* __restrict__ hb, const int2* __restrict__ rps,
        const int* __restrict__ col, const float* __restrict__ dis,
        const float* __restrict__ bias, float* __restrict__ out, int n) {
    int wid = threadIdx.x >> 6;
    int lane = threadIdx.x & 63;
    int v = blockIdx.x * 4 + wid;
    if (v >= n) return;
    float acc = bfu(hb[(size_t)v * 64 + lane]);
    int2 se = rps[v];
    int s = __builtin_amdgcn_readfirstlane(se.x);
    int e = __builtin_amdgcn_readfirstlane(se.y);
    int k = s;
    for (; k + 16 <= e; k += 16) {
        ushort m[16];
#pragma unroll
        for (int j = 0; j < 16; ++j) m[j] = hb[(size_t)col[k + j] * 64 + lane];
#pragma unroll
        for (int j = 0; j < 16; ++j) acc += bfu(m[j]);
    }
    if (k + 8 <= e) {
        ushort m[8];
#pragma unroll
        for (int j = 0; j < 8; ++j) m[j] = hb[(size_t)col[k + j] * 64 + lane];
#pragma unroll
        for (int j = 0; j < 8; ++j) acc += bfu(m[j]);
        k += 8;
    }
    for (; k < e; ++k) acc += bfu(hb[(size_t)col[k] * 64 + lane]);
    float val = dis[v] * acc + bias[lane];
    float m = val;
    for (int off = 32; off; off >>= 1) m = fmaxf(m, __shfl_xor(m, off, 64));
    float ex = expf(val - m);
    float ss = ex;
    for (int off = 32; off; off >>= 1) ss += __shfl_xor(ss, off, 64);
    __builtin_nontemporal_store(val - m - logf(ss), &out[(size_t)v * 64 + lane]);
}

// ---------------- launch ----------------

extern "C" void kernel_launch(void* const* d_in, const int* in_sizes, int n_in,
                              void* d_out, int out_size, void* d_ws, size_t ws_size,
                              hipStream_t stream) {
    const float* x  = (const float*)d_in[0];
    const float* W1 = (const float*)d_in[1];
    const float* b1 = (const float*)d_in[2];
    const float* W2 = (const float*)d_in[3];
    const float* b2 = (const float*)d_in[4];
    const float* W3 = (const float*)d_in[5];
    const float* b3 = (const float*)d_in[6];
    const int*   ei = (const int*)d_in[7];

    const int N = in_sizes[0] / 128;
    const int E = in_sizes[7] / 2;
    const int* srcv = ei;
    const int* dstv = ei + E;
    const int NB  = (N + 255) >> 8;          // 256-node buckets
    const int nbE = (E + EPB - 1) / EPB;
    const size_t PLSZ = (size_t)N * 64;      // ushorts per 64-feature plane

    char* ws = (char*)d_ws;
    size_t off = 0;
    auto alloc = [&](size_t bytes) -> void* {
        void* p = ws + off;
        off += (bytes + 255) & ~(size_t)255;
        return p;
    };
    float*    dis   = (float*)alloc((size_t)N * 4);
    int2*     rps   = (int2*)alloc((size_t)N * 8);
    int*      bcnt  = (int*)alloc((size_t)NB * 4);
    int*      col   = (int*)alloc((size_t)NB * CAP * 4);
    uint64_t* pairs = (uint64_t*)alloc((size_t)NB * CAP * 8);
    ushort*   Wt1   = (ushort*)alloc(128 * 128 * 2);
    ushort*   Wt2   = (ushort*)alloc(128 * 128 * 2);
    ushort*   Wt3   = (ushort*)alloc(64 * 128 * 2);
    ushort*   hsA   = (ushort*)alloc(PLSZ * 2 * 2);   // GEMM1/2 out (2 planes), gather src
    ushort*   hbB   = (ushort*)alloc(PLSZ * 2 * 2);   // agg out (2 planes) / GEMM in
    ushort*   hs3   = (ushort*)alloc(PLSZ * 2);       // GEMM3 out (flat [N][64])
    float*    outp  = (float*)d_out;

    // --- CSR build (2 kernels + counter clear) ---
    (void)hipMemsetAsync(bcnt, 0, (size_t)NB * 4, stream);
    k_part_prep<<<nbE + 3, 256, 0, stream>>>(srcv, dstv, bcnt, pairs, E, nbE,
                                             W1, W2, W3, Wt1, Wt2, Wt3);
    k_bfinish<<<NB, 256, 0, stream>>>(pairs, bcnt, rps, dis, col, N);

    // --- 3 GCN layers (agg split into per-plane dispatches for L2 footprint) ---
    int gblk = (N + 63) / 64;
    int ablk = (N + 3) / 4;
    k_gemm_mfma<128, 0><<<gblk, 256, 0, stream>>>(x, Wt1, dis, hsA, N, PLSZ);
    k_agg_plane<<<ablk, 256, 0, stream>>>(hsA,        rps, col, dis, b1,      hbB,        N);
    k_agg_plane<<<ablk, 256, 0, stream>>>(hsA + PLSZ, rps, col, dis, b1 + 64, hbB + PLSZ, N);
    k_gemm_mfma<128, 1><<<gblk, 256, 0, stream>>>(hbB, Wt2, dis, hsA, N, PLSZ);
    k_agg_plane<<<ablk, 256, 0, stream>>>(hsA,        rps, col, dis, b2,      hbB,        N);
    k_agg_plane<<<ablk, 256, 0, stream>>>(hsA + PLSZ, rps, col, dis, b2 + 64, hbB + PLSZ, N);
    k_gemm_mfma<64, 1><<<gblk, 256, 0, stream>>>(hbB, Wt3, dis, hs3, N, PLSZ);
    k_agg_lsm64<<<ablk, 256, 0, stream>>>(hs3, rps, col, dis, b3, outp, N);
}

// Round 14
// 196.801 us; speedup vs baseline: 5.4797x; 1.0727x over previous
//
#include <hip/hip_runtime.h>
#include <hip/hip_bf16.h>
#include <cstdint>

typedef unsigned int uint32;
typedef unsigned short ushort;
typedef __attribute__((ext_vector_type(8))) short short8;   // 8 bf16 (4 VGPRs)
typedef __attribute__((ext_vector_type(4))) float f32x4;    // MFMA C/D

#define EPB 4096      // edges per block in partition kernel
#define CAP 8192      // slots per 256-node bucket (mean ~4081, 2x headroom)

__device__ inline ushort bf16r(float f) {
    uint32 u = __float_as_uint(f);
    u += 0x7fff + ((u >> 16) & 1);
    return (ushort)(u >> 16);
}
__device__ inline uint32 pack_bf16(float a, float b) {
    return (uint32)bf16r(a) | ((uint32)bf16r(b) << 16);
}
__device__ inline float bf_lo(uint32 w) { return __uint_as_float(w << 16); }
__device__ inline float bf_hi(uint32 w) { return __uint_as_float(w & 0xffff0000u); }

// ---------------- K1: direct bucket partition + W-prep ----------------
// bucket = dst >> 8 (256-node windows, NB<=256). pairs bucket-strided by CAP.

__global__ __launch_bounds__(256) void k_part_prep(
        const int* __restrict__ srcv, const int* __restrict__ dstv,
        int* __restrict__ bcnt, uint64_t* __restrict__ pairs, int e, int nbE,
        const float* __restrict__ W1, const float* __restrict__ W2, const float* __restrict__ W3,
        ushort* __restrict__ Wt1, ushort* __restrict__ Wt2, ushort* __restrict__ Wt3) {
    int bid = blockIdx.x, t = threadIdx.x;
    if (bid >= nbE) {
        int wb = bid - nbE;
        const float* W = wb == 0 ? W1 : (wb == 1 ? W2 : W3);
        ushort* Wt = wb == 0 ? Wt1 : (wb == 1 ? Wt2 : Wt3);
        int F = wb == 2 ? 64 : 128;
        for (int i = t; i < 128 * F; i += 256) {
            int k = i / F, c = i % F;
            Wt[c * 128 + k] = bf16r(W[i]);
        }
        return;
    }
    __shared__ int h[256], base[256], cur[256];
    h[t] = 0; cur[t] = 0;
    __syncthreads();
    int s[EPB / 256], d[EPB / 256];
    int b0 = bid * EPB;
#pragma unroll
    for (int i = 0; i < EPB / 256; ++i) {
        int idx = b0 + i * 256 + t;
        if (idx < e) {
            s[i] = srcv[idx]; d[i] = dstv[idx];
            atomicAdd(&h[d[i] >> 8], 1);
        } else d[i] = -1;
    }
    __syncthreads();
    base[t] = h[t] ? atomicAdd(&bcnt[t], h[t]) : 0;
    __syncthreads();
#pragma unroll
    for (int i = 0; i < EPB / 256; ++i) {
        if (d[i] >= 0) {
            int b = d[i] >> 8;
            int sl = base[b] + atomicAdd(&cur[b], 1);
            if (sl < CAP)
                pairs[(size_t)b * CAP + sl] =
                    (uint64_t)(unsigned)s[i] | ((uint64_t)(unsigned)d[i] << 32);
        }
    }
}

// ---------------- K2: per-bucket finish — local CSR into bucket-strided col ----------------

__global__ __launch_bounds__(256) void k_bfinish(const uint64_t* __restrict__ pairs,
                                                 const int* __restrict__ bcnt,
                                                 int2* __restrict__ rps, float* __restrict__ dis,
                                                 int* __restrict__ col, int n) {
    __shared__ int c[256], sc[256], cur[256];
    int t = threadIdx.x;
    c[t] = 0; cur[t] = 0;
    __syncthreads();
    int wb = blockIdx.x << 8;
    int e0 = blockIdx.x * CAP;
    int e1 = e0 + min(bcnt[blockIdx.x], CAP);
    for (int i = e0 + t; i < e1; i += 256)
        atomicAdd(&c[(int)(pairs[i] >> 32) - wb], 1);
    __syncthreads();
    int own = c[t];
    sc[t] = own;
    __syncthreads();
    for (int off = 1; off < 256; off <<= 1) {
        int a = (t >= off) ? sc[t - off] : 0;
        __syncthreads();
        sc[t] += a;
        __syncthreads();
    }
    int start = blockIdx.x * CAP + sc[t] - own;
    __syncthreads();
    sc[t] = start;
    int v = wb + t;
    if (v < n) {
        rps[v] = make_int2(start, start + own);
        dis[v] = rsqrtf((float)(own + 1));
    }
    __syncthreads();
    for (int i = e0 + t; i < e1; i += 256) {
        uint64_t p = pairs[i];
        int bl = (int)(p >> 32) - wb;
        int sl = atomicAdd(&cur[bl], 1);
        col[sc[bl] + sl] = (int)(uint32)p;
    }
}

// ------- MFMA GEMM: Yb[r][c] = bf16( dis[r] * sum_k X[r][k] * W[k][c] ) -------
// K=128. 4 waves, 16 rows/wave, 64 rows/block. Wt = W^T bf16 [FOUT][128].

template <int FOUT, bool BF16IN>
__global__ __launch_bounds__(256) void k_gemm_mfma(
        const void* __restrict__ Xv, const ushort* __restrict__ Wt,
        const float* __restrict__ dis, ushort* __restrict__ Yb, int n) {
    constexpr int CT = FOUT / 16;
    int lane = threadIdx.x & 63;
    int wv = threadIdx.x >> 6;
    int r16 = lane & 15, kg = lane >> 4;
    int rowA = blockIdx.x * 64 + wv * 16 + r16;
    int ra = min(rowA, n - 1);
    short8 afr[4];
    if (BF16IN) {
        const ushort* Xb = (const ushort*)Xv;
#pragma unroll
        for (int ks = 0; ks < 4; ++ks)
            afr[ks] = *(const short8*)(Xb + (size_t)ra * 128 + ks * 32 + kg * 8);
    } else {
        const float* Xf = (const float*)Xv;
#pragma unroll
        for (int ks = 0; ks < 4; ++ks) {
            const float* p = Xf + (size_t)ra * 128 + ks * 32 + kg * 8;
            float4 f0 = *(const float4*)p;
            float4 f1 = *(const float4*)(p + 4);
            short8 a;
            a[0] = (short)bf16r(f0.x); a[1] = (short)bf16r(f0.y);
            a[2] = (short)bf16r(f0.z); a[3] = (short)bf16r(f0.w);
            a[4] = (short)bf16r(f1.x); a[5] = (short)bf16r(f1.y);
            a[6] = (short)bf16r(f1.z); a[7] = (short)bf16r(f1.w);
            afr[ks] = a;
        }
    }
    f32x4 acc[CT];
#pragma unroll
    for (int c = 0; c < CT; ++c) acc[c] = (f32x4){0.f, 0.f, 0.f, 0.f};
#pragma unroll
    for (int ks = 0; ks < 4; ++ks) {
#pragma unroll
        for (int c = 0; c < CT; ++c) {
            short8 b = *(const short8*)(Wt + (c * 16 + r16) * 128 + ks * 32 + kg * 8);
            acc[c] = __builtin_amdgcn_mfma_f32_16x16x32_bf16(afr[ks], b, acc[c], 0, 0, 0);
        }
    }
    int rbase = blockIdx.x * 64 + wv * 16 + kg * 4;
#pragma unroll
    for (int j = 0; j < 4; ++j) {
        int row = rbase + j;
        if (row < n) {
            float d = dis[row];
#pragma unroll
            for (int c = 0; c < CT; ++c)
                Yb[(size_t)row * FOUT + c * 16 + r16] = bf16r(acc[c][j] * d);
        }
    }
}

// ---------------- aggregation: 2 rows per load instruction (F=128) ----------------
// wave = 2 row-groups x 32 lanes x uint2(8B) = 2 x 256B rows per gather instr.
// outb[v] = bf16( relu( dis[v] * (hs[v] + sum_nbr hs[u]) + b ) )

__global__ __launch_bounds__(256) void k_agg_relu128(
        const uint32* __restrict__ hb, const int2* __restrict__ rps,
        const int* __restrict__ col, const float* __restrict__ dis,
        const float* __restrict__ bias, uint32* __restrict__ outb, int n) {
    int wid = threadIdx.x >> 6;
    int lane = threadIdx.x & 63;
    int grp = lane >> 5;        // 2 row-groups
    int fl  = lane & 31;        // feature-quad slot: features 4*fl .. 4*fl+3
    int v = blockIdx.x * 4 + wid;
    if (v >= n) return;
    int2 se = rps[v];
    int s = __builtin_amdgcn_readfirstlane(se.x);
    int e = __builtin_amdgcn_readfirstlane(se.y);
    float a0 = 0.f, a1 = 0.f, a2 = 0.f, a3 = 0.f;
    int k = s;
    for (; k + 16 <= e; k += 16) {
        uint2 m[8];
#pragma unroll
        for (int j = 0; j < 8; ++j) {
            int r = col[k + j * 2 + grp];
            m[j] = *(const uint2*)(hb + (size_t)r * 64 + fl * 2);
        }
#pragma unroll
        for (int j = 0; j < 8; ++j) {
            a0 += bf_lo(m[j].x); a1 += bf_hi(m[j].x);
            a2 += bf_lo(m[j].y); a3 += bf_hi(m[j].y);
        }
    }
    if (k + 8 <= e) {
        uint2 m[4];
#pragma unroll
        for (int j = 0; j < 4; ++j) {
            int r = col[k + j * 2 + grp];
            m[j] = *(const uint2*)(hb + (size_t)r * 64 + fl * 2);
        }
#pragma unroll
        for (int j = 0; j < 4; ++j) {
            a0 += bf_lo(m[j].x); a1 += bf_hi(m[j].x);
            a2 += bf_lo(m[j].y); a3 += bf_hi(m[j].y);
        }
        k += 8;
    }
    for (; k < e; k += 2) {
        int idx = k + grp;
        bool valid = idx < e;
        int r = col[min(idx, e - 1)];
        uint2 m = *(const uint2*)(hb + (size_t)r * 64 + fl * 2);
        if (valid) {
            a0 += bf_lo(m.x); a1 += bf_hi(m.x);
            a2 += bf_lo(m.y); a3 += bf_hi(m.y);
        }
    }
    // combine the 2 row-groups
    a0 += __shfl_xor(a0, 32, 64);
    a1 += __shfl_xor(a1, 32, 64);
    a2 += __shfl_xor(a2, 32, 64);
    a3 += __shfl_xor(a3, 32, 64);
    // self-loop + bias + relu (post-reduce so it's counted once)
    uint2 mv = *(const uint2*)(hb + (size_t)v * 64 + fl * 2);
    a0 += bf_lo(mv.x); a1 += bf_hi(mv.x);
    a2 += bf_lo(mv.y); a3 += bf_hi(mv.y);
    float d = dis[v];
    float4 bb = *(const float4*)(bias + fl * 4);
    float o0 = fmaxf(d * a0 + bb.x, 0.f);
    float o1 = fmaxf(d * a1 + bb.y, 0.f);
    float o2 = fmaxf(d * a2 + bb.z, 0.f);
    float o3 = fmaxf(d * a3 + bb.w, 0.f);
    if (grp == 0) {
        uint32* op = outb + (size_t)v * 64 + fl * 2;
        __builtin_nontemporal_store(pack_bf16(o0, o1), op);
        __builtin_nontemporal_store(pack_bf16(o2, o3), op + 1);
    }
}

// ---------------- final layer: 4 rows per load instruction (F=64) + log_softmax ----------------
// wave = 4 row-groups x 16 lanes x uint2(8B) = 4 x 128B rows per gather instr.

__global__ __launch_bounds__(256) void k_agg_lsm64(
        const ushort* __restrict__ hb3, const int2* __restrict__ rps,
        const int* __restrict__ col, const float* __restrict__ dis,
        const float* __restrict__ bias, float* __restrict__ out, int n) {
    const uint32* hb = (const uint32*)hb3;   // row = 32 words
    int wid = threadIdx.x >> 6;
    int lane = threadIdx.x & 63;
    int grp = lane >> 4;        // 4 row-groups
    int fl  = lane & 15;        // features 4*fl .. 4*fl+3
    int v = blockIdx.x * 4 + wid;
    if (v >= n) return;
    int2 se = rps[v];
    int s = __builtin_amdgcn_readfirstlane(se.x);
    int e = __builtin_amdgcn_readfirstlane(se.y);
    float a0 = 0.f, a1 = 0.f, a2 = 0.f, a3 = 0.f;
    int k = s;
    for (; k + 16 <= e; k += 16) {
        uint2 m[4];
#pragma unroll
        for (int j = 0; j < 4; ++j) {
            int r = col[k + j * 4 + grp];
            m[j] = *(const uint2*)(hb + (size_t)r * 32 + fl * 2);
        }
#pragma unroll
        for (int j = 0; j < 4; ++j) {
            a0 += bf_lo(m[j].x); a1 += bf_hi(m[j].x);
            a2 += bf_lo(m[j].y); a3 += bf_hi(m[j].y);
        }
    }
    for (; k < e; k += 4) {
        int idx = k + grp;
        bool valid = idx < e;
        int r = col[min(idx, e - 1)];
        uint2 m = *(const uint2*)(hb + (size_t)r * 32 + fl * 2);
        if (valid) {
            a0 += bf_lo(m.x); a1 += bf_hi(m.x);
            a2 += bf_lo(m.y); a3 += bf_hi(m.y);
        }
    }
    // combine the 4 row-groups
    a0 += __shfl_xor(a0, 16, 64); a0 += __shfl_xor(a0, 32, 64);
    a1 += __shfl_xor(a1, 16, 64); a1 += __shfl_xor(a1, 32, 64);
    a2 += __shfl_xor(a2, 16, 64); a2 += __shfl_xor(a2, 32, 64);
    a3 += __shfl_xor(a3, 16, 64); a3 += __shfl_xor(a3, 32, 64);
    // self-loop + bias
    uint2 mv = *(const uint2*)(hb + (size_t)v * 32 + fl * 2);
    a0 += bf_lo(mv.x); a1 += bf_hi(mv.x);
    a2 += bf_lo(mv.y); a3 += bf_hi(mv.y);
    float d = dis[v];
    float4 bb = *(const float4*)(bias + fl * 4);
    float v0 = d * a0 + bb.x;
    float v1 = d * a1 + bb.y;
    float v2 = d * a2 + bb.z;
    float v3 = d * a3 + bb.w;
    // log_softmax over 64 features (16 lanes x 4; groups hold replicas)
    float mx = fmaxf(fmaxf(v0, v1), fmaxf(v2, v3));
    for (int off = 8; off; off >>= 1) mx = fmaxf(mx, __shfl_xor(mx, off, 64));
    float ss = expf(v0 - mx) + expf(v1 - mx) + expf(v2 - mx) + expf(v3 - mx);
    for (int off = 8; off; off >>= 1) ss += __shfl_xor(ss, off, 64);
    float ls = mx + logf(ss);
    if (grp == 0) {
        float* op = out + (size_t)v * 64 + fl * 4;
        __builtin_nontemporal_store(v0 - ls, op);
        __builtin_nontemporal_store(v1 - ls, op + 1);
        __builtin_nontemporal_store(v2 - ls, op + 2);
        __builtin_nontemporal_store(v3 - ls, op + 3);
    }
}

// ---------------- launch ----------------

extern "C" void kernel_launch(void* const* d_in, const int* in_sizes, int n_in,
                              void* d_out, int out_size, void* d_ws, size_t ws_size,
                              hipStream_t stream) {
    const float* x  = (const float*)d_in[0];
    const float* W1 = (const float*)d_in[1];
    const float* b1 = (const float*)d_in[2];
    const float* W2 = (const float*)d_in[3];
    const float* b2 = (const float*)d_in[4];
    const float* W3 = (const float*)d_in[5];
    const float* b3 = (const float*)d_in[6];
    const int*   ei = (const int*)d_in[7];

    const int N = in_sizes[0] / 128;
    const int E = in_sizes[7] / 2;
    const int* srcv = ei;
    const int* dstv = ei + E;
    const int NB  = (N + 255) >> 8;          // 256-node buckets
    const int nbE = (E + EPB - 1) / EPB;

    char* ws = (char*)d_ws;
    size_t off = 0;
    auto alloc = [&](size_t bytes) -> void* {
        void* p = ws + off;
        off += (bytes + 255) & ~(size_t)255;
        return p;
    };
    float*    dis   = (float*)alloc((size_t)N * 4);
    int2*     rps   = (int2*)alloc((size_t)N * 8);
    int*      bcnt  = (int*)alloc((size_t)NB * 4);
    int*      col   = (int*)alloc((size_t)NB * CAP * 4);
    uint64_t* pairs = (uint64_t*)alloc((size_t)NB * CAP * 8);
    ushort*   Wt1   = (ushort*)alloc(128 * 128 * 2);
    ushort*   Wt2   = (ushort*)alloc(128 * 128 * 2);
    ushort*   Wt3   = (ushort*)alloc(64 * 128 * 2);
    ushort*   hsb   = (ushort*)alloc((size_t)N * 128 * 2);  // GEMM out / gather src
    ushort*   hbX   = (ushort*)alloc((size_t)N * 128 * 2);  // agg out / GEMM in
    ushort*   hs3   = (ushort*)alloc((size_t)N * 64 * 2);   // GEMM3 out
    float*    outp  = (float*)d_out;

    // --- CSR build (2 kernels + counter clear) ---
    (void)hipMemsetAsync(bcnt, 0, (size_t)NB * 4, stream);
    k_part_prep<<<nbE + 3, 256, 0, stream>>>(srcv, dstv, bcnt, pairs, E, nbE,
                                             W1, W2, W3, Wt1, Wt2, Wt3);
    k_bfinish<<<NB, 256, 0, stream>>>(pairs, bcnt, rps, dis, col, N);

    // --- 3 GCN layers ---
    int gblk = (N + 63) / 64;
    int ablk = (N + 3) / 4;
    k_gemm_mfma<128, false><<<gblk, 256, 0, stream>>>(x, Wt1, dis, hsb, N);
    k_agg_relu128<<<ablk, 256, 0, stream>>>((const uint32*)hsb, rps, col, dis, b1, (uint32*)hbX, N);
    k_gemm_mfma<128, true><<<gblk, 256, 0, stream>>>(hbX, Wt2, dis, hsb, N);
    k_agg_relu128<<<ablk, 256, 0, stream>>>((const uint32*)hsb, rps, col, dis, b2, (uint32*)hbX, N);
    k_gemm_mfma<64, true><<<gblk, 256, 0, stream>>>(hbX, Wt3, dis, hs3, N);
    k_agg_lsm64<<<ablk, 256, 0, stream>>>(hs3, rps, col, dis, b3, outp, N);
}